// Round 4
// baseline (42.064 us; speedup 1.0000x reference)
//
#include <hip/hip_runtime.h>
#include <math.h>

// Cox partial-likelihood loss, N = 16384 — sorted-chunk suffix-sum scheme.
//   T = |y|, E = (y > 0), theta = y_hat, e = exp(theta)
//   risk[i] = sum over 64 sorted chunks c of suffix_c[ lower_bound_c(T_i) ]
//   loss = -mean((theta - log(risk)) * E)
//
// K0: 64 blocks x 256 thr — per-chunk bitonic sort by T (36 stages, 4-wave
//     barriers) + inclusive suffix sum of e -> sortedT[N], sortedS[N] in ws.
// K1: 64 blocks x 256 thr — stage BOTH tables into LDS (128 KB), each thread
//     lower-bounds all 64 chunks in LDS (64 independent 9-step chains -> ILP
//     hides LDS latency), accumulates risk in-thread, computes its term,
//     block-reduces, one atomicAdd(out) per block.

#define CSZ  256
#define NCH  64
#define N_   16384

// ---------------- K0: per-chunk sort + suffix scan ----------------
__global__ void __launch_bounds__(CSZ) cox_sort(
        const float* __restrict__ y_hat, const float* __restrict__ y,
        float* __restrict__ sortedT, float* __restrict__ sortedS,
        float* __restrict__ out) {
    __shared__ float sT[CSZ];
    __shared__ float sE[CSZ];
    const int tid = threadIdx.x;
    const int base = blockIdx.x * CSZ;

    sT[tid] = fabsf(y[base + tid]);
    sE[tid] = expf(y_hat[base + tid]);
    if (base + tid == 0) out[0] = 0.0f;
    __syncthreads();

    // bitonic sort ascending by T, e rides along (36 compare stages)
    for (int k = 2; k <= CSZ; k <<= 1) {
        for (int j = k >> 1; j > 0; j >>= 1) {
            int ixj = tid ^ j;
            if (ixj > tid) {
                float t0 = sT[tid], t1 = sT[ixj];
                bool up = ((tid & k) == 0);
                if (up ? (t0 > t1) : (t0 < t1)) {
                    sT[tid] = t1; sT[ixj] = t0;
                    float e0 = sE[tid]; sE[tid] = sE[ixj]; sE[ixj] = e0;
                }
            }
            __syncthreads();
        }
    }

    // inclusive suffix sum of sE (doubling, 8 steps)
    for (int d = 1; d < CSZ; d <<= 1) {
        float add = (tid + d < CSZ) ? sE[tid + d] : 0.0f;
        __syncthreads();
        sE[tid] += add;
        __syncthreads();
    }

    sortedT[base + tid] = sT[tid];
    sortedS[base + tid] = sE[tid];
}

// ---------------- K1: LDS-resident 64-way search + fused loss reduce --------
__global__ void __launch_bounds__(256) cox_search(
        const float* __restrict__ y_hat, const float* __restrict__ y,
        const float* __restrict__ sortedT, const float* __restrict__ sortedS,
        float* __restrict__ out, int n) {
    __shared__ float sT[N_];            // 64 KB: all sorted T
    __shared__ float sS[N_];            // 64 KB: all suffix sums
    __shared__ float wsum[4];

    const int tid = threadIdx.x;

    // stage both tables (float4, coalesced, L2-resident source)
    {
        const float4* gT = (const float4*)sortedT;
        const float4* gS = (const float4*)sortedS;
        float4* lT = (float4*)sT;
        float4* lS = (float4*)sS;
        #pragma unroll
        for (int k = tid; k < N_ / 4; k += 256) {
            lT[k] = gT[k];
            lS[k] = gS[k];
        }
    }
    __syncthreads();

    const int i = blockIdx.x * 256 + tid;
    const float Ti = fabsf(y[i]);

    float risk = 0.0f;
    #pragma unroll 8
    for (int c = 0; c < NCH; ++c) {
        const float* Tc = &sT[c << 8];
        // branchless lower_bound: first pos with Tc[pos] >= Ti, pos in [0,256]
        int pos = 0;
        #pragma unroll
        for (int half = CSZ >> 1; half >= 1; half >>= 1)
            if (Tc[pos + half - 1] < Ti) pos += half;
        if (Tc[pos] < Ti) pos += 1;
        risk += (pos < CSZ) ? sS[(c << 8) + pos] : 0.0f;
    }

    float E = (y[i] > 0.0f) ? 1.0f : 0.0f;
    float term = (y_hat[i] - logf(risk)) * E;

    // block reduce: wave-64 butterfly, then cross-wave via LDS
    #pragma unroll
    for (int off = 32; off >= 1; off >>= 1)
        term += __shfl_down(term, off, 64);
    if ((tid & 63) == 0) wsum[tid >> 6] = term;
    __syncthreads();
    if (tid == 0) {
        float s = wsum[0] + wsum[1] + wsum[2] + wsum[3];
        atomicAdd(out, -s / (float)n);
    }
}

extern "C" void kernel_launch(void* const* d_in, const int* in_sizes, int n_in,
                              void* d_out, int out_size, void* d_ws, size_t ws_size,
                              hipStream_t stream) {
    const float* y_hat = (const float*)d_in[0];
    const float* y     = (const float*)d_in[1];
    float* out = (float*)d_out;
    const int n = in_sizes[0];   // 16384

    float* sortedT = (float*)d_ws;
    float* sortedS = sortedT + n;

    cox_sort<<<n / CSZ, CSZ, 0, stream>>>(y_hat, y, sortedT, sortedS, out);
    cox_search<<<n / 256, 256, 0, stream>>>(y_hat, y, sortedT, sortedS, out, n);
}

// Round 5
// 20.792 us; speedup vs baseline: 2.0231x; 2.0231x over previous
//
#include <hip/hip_runtime.h>
#include <math.h>

// Cox partial-likelihood loss, N = 16384 — sorted-chunk suffix-sum scheme.
//   T = |y|, E = (y > 0), theta = y_hat, e = exp(theta)
//   risk[i] = sum over 64 sorted chunks c of suffix_c[ lower_bound_c(T_i) ]
//   loss = -mean((theta - log(risk)) * E)
//
// K0: 64 blocks x 256 thr — per-chunk bitonic sort by T + inclusive suffix
//     sum of e -> sortedT[N], sortedS[N]; zeroes out[0].
// K1: 256 blocks x 1024 thr — each block owns 64 i's; stages BOTH tables in
//     LDS (128 KB, 1 block/CU but 256 blocks -> all CUs busy, 16 waves/block
//     for TLP); thread group g (16 groups) searches 4 chunks for its i;
//     LDS reduce across groups; wave 0 computes terms, block-reduces, one
//     atomicAdd(out) per block.

#define CSZ  256
#define NCH  64
#define N_   16384
#define IPB  64          // i's per K1 block

// ---------------- K0: per-chunk sort + suffix scan ----------------
__global__ void __launch_bounds__(CSZ) cox_sort(
        const float* __restrict__ y_hat, const float* __restrict__ y,
        float* __restrict__ sortedT, float* __restrict__ sortedS,
        float* __restrict__ out) {
    __shared__ float sT[CSZ];
    __shared__ float sE[CSZ];
    const int tid = threadIdx.x;
    const int base = blockIdx.x * CSZ;

    sT[tid] = fabsf(y[base + tid]);
    sE[tid] = expf(y_hat[base + tid]);
    if (base + tid == 0) out[0] = 0.0f;
    __syncthreads();

    // bitonic sort ascending by T, e rides along (36 compare stages)
    for (int k = 2; k <= CSZ; k <<= 1) {
        for (int j = k >> 1; j > 0; j >>= 1) {
            int ixj = tid ^ j;
            if (ixj > tid) {
                float t0 = sT[tid], t1 = sT[ixj];
                bool up = ((tid & k) == 0);
                if (up ? (t0 > t1) : (t0 < t1)) {
                    sT[tid] = t1; sT[ixj] = t0;
                    float e0 = sE[tid]; sE[tid] = sE[ixj]; sE[ixj] = e0;
                }
            }
            __syncthreads();
        }
    }

    // inclusive suffix sum of sE (doubling, 8 steps)
    for (int d = 1; d < CSZ; d <<= 1) {
        float add = (tid + d < CSZ) ? sE[tid + d] : 0.0f;
        __syncthreads();
        sE[tid] += add;
        __syncthreads();
    }

    sortedT[base + tid] = sT[tid];
    sortedS[base + tid] = sE[tid];
}

// ---------------- K1: all-CU LDS search + fused loss reduce ----------------
__global__ void __launch_bounds__(1024, 4) cox_search(
        const float* __restrict__ y_hat, const float* __restrict__ y,
        const float* __restrict__ sortedT, const float* __restrict__ sortedS,
        float* __restrict__ out, int n) {
    __shared__ float sT[N_];              // 64 KB: all sorted T
    __shared__ float sS[N_];              // 64 KB: all suffix sums
    __shared__ float part[16][IPB];       // 4 KB: per-group partial risks

    const int tid = threadIdx.x;

    // stage both tables (float4, coalesced, L2-resident source)
    {
        const float4* gT = (const float4*)sortedT;
        const float4* gS = (const float4*)sortedS;
        float4* lT = (float4*)sT;
        float4* lS = (float4*)sS;
        #pragma unroll
        for (int k = tid; k < N_ / 4; k += 1024) {
            lT[k] = gT[k];
            lS[k] = gS[k];
        }
    }
    __syncthreads();

    const int il = tid & 63;              // which of this block's 64 i's
    const int g  = tid >> 6;              // chunk group 0..15
    const int i  = blockIdx.x * IPB + il;
    const float Ti = fabsf(y[i]);

    float r = 0.0f;
    #pragma unroll
    for (int cc = 0; cc < 4; ++cc) {
        const int c = (g << 2) + cc;
        const float* Tc = &sT[c << 8];
        // branchless lower_bound: first pos with Tc[pos] >= Ti, pos in [0,256]
        int pos = 0;
        #pragma unroll
        for (int half = CSZ >> 1; half >= 1; half >>= 1)
            if (Tc[pos + half - 1] < Ti) pos += half;
        if (Tc[pos] < Ti) pos += 1;
        r += (pos < CSZ) ? sS[(c << 8) + pos] : 0.0f;
    }
    part[g][il] = r;
    __syncthreads();

    if (tid < 64) {
        float risk = 0.0f;
        #pragma unroll
        for (int g2 = 0; g2 < 16; ++g2) risk += part[g2][tid];
        float E = (y[i] > 0.0f) ? 1.0f : 0.0f;
        float term = (y_hat[i] - logf(risk)) * E;
        #pragma unroll
        for (int off = 32; off >= 1; off >>= 1)
            term += __shfl_down(term, off, 64);
        if (tid == 0) atomicAdd(out, -term / (float)n);
    }
}

extern "C" void kernel_launch(void* const* d_in, const int* in_sizes, int n_in,
                              void* d_out, int out_size, void* d_ws, size_t ws_size,
                              hipStream_t stream) {
    const float* y_hat = (const float*)d_in[0];
    const float* y     = (const float*)d_in[1];
    float* out = (float*)d_out;
    const int n = in_sizes[0];   // 16384

    float* sortedT = (float*)d_ws;
    float* sortedS = sortedT + n;

    cox_sort<<<n / CSZ, CSZ, 0, stream>>>(y_hat, y, sortedT, sortedS, out);
    cox_search<<<n / IPB, 1024, 0, stream>>>(y_hat, y, sortedT, sortedS, out, n);
}